// Round 1
// baseline (3556.819 us; speedup 1.0000x reference)
//
#include <hip/hip_runtime.h>
#include <math.h>

namespace {

constexpr int NATOMS = 1000000;
constexpr int NBATCH = 32768;
constexpr int kCounts[11] = {10000,250000,300000,250000,120000,40000,15000,8000,4000,2000,1000};
constexpr int kStarts[11] = {0,10000,260000,560000,810000,930000,970000,985000,993000,997000,999000};

struct AdjPtrs { const int* p[10]; };

__device__ __forceinline__ unsigned enc_f32(float x) {
    unsigned u = __float_as_uint(x);
    return (u & 0x80000000u) ? ~u : (u | 0x80000000u);
}
__device__ __forceinline__ float dec_f32(unsigned u) {
    return (u & 0x80000000u) ? __uint_as_float(u & 0x7FFFFFFFu) : __uint_as_float(~u);
}

// ---------------------------------------------------------------------------
// Graph conv + ReLU + BN.  One block = 64 atoms of a single degree.
// LDS holds self rows and neighbor-sum rows, k-major [CI][64].
// Thread (c = t&63, g = t>>6) computes out[g*16+i][c], i in 0..15.
// ---------------------------------------------------------------------------
template<int CI>
__global__ __launch_bounds__(256) void conv_kernel(
    const float* __restrict__ x, AdjPtrs adj,
    const float* __restrict__ W, const float* __restrict__ B,
    const float* __restrict__ bng, const float* __restrict__ bnb,
    const float* __restrict__ bnm, const float* __restrict__ bnv,
    float* __restrict__ out)
{
    __shared__ __align__(16) float s_self[CI][64];
    __shared__ __align__(16) float s_rel[CI][64];

    int d = 0, rem = blockIdx.x;
    for (;;) { int nb = (kCounts[d] + 63) >> 6; if (rem < nb) break; rem -= nb; ++d; }
    const int j0 = rem << 6;
    const int nA = min(64, kCounts[d] - j0);
    const int a0 = kStarts[d] + j0;
    const int t = threadIdx.x;

    // stage self rows (contiguous global region -> transposed LDS)
    for (int e = t; e < nA * CI; e += 256) {
        int ai = e / CI, k = e - ai * CI;
        s_self[k][ai] = x[(size_t)(a0 + ai) * CI + k];
    }

    // stage neighbor-sum rows: 4 threads per atom accumulate in registers
    if (d > 0) {
        constexpr int NQ = (CI + 3) / 4;
        const int ai = t >> 2, g4 = t & 3;
        if (ai < nA) {
            float r[NQ];
            #pragma unroll
            for (int q = 0; q < NQ; ++q) r[q] = 0.f;
            const int* __restrict__ ad = adj.p[d - 1];
            for (int n = 0; n < d; ++n) {
                const int idx = ad[(size_t)(j0 + ai) * d + n];
                const float* __restrict__ xr = x + (size_t)idx * CI;
                #pragma unroll
                for (int q = 0; q < NQ; ++q) {
                    const int e = g4 + 4 * q;
                    if (e < CI) r[q] += xr[e];
                }
            }
            #pragma unroll
            for (int q = 0; q < NQ; ++q) {
                const int e = g4 + 4 * q;
                if (e < CI) s_rel[e][ai] = r[q];
            }
        }
    }
    __syncthreads();

    const int c = t & 63, g = t >> 6;
    float acc[16];
    #pragma unroll
    for (int i = 0; i < 16; ++i) acc[i] = 0.f;

    if (d == 0) {
        const float* __restrict__ Ws = W + (size_t)(2 * 10) * CI * 64;
        for (int k = 0; k < CI; ++k) {
            const float ws = Ws[k * 64 + c];
            #pragma unroll
            for (int ii = 0; ii < 4; ++ii) {
                const float4 s4 = *reinterpret_cast<const float4*>(&s_self[k][g * 16 + ii * 4]);
                acc[ii*4+0] = fmaf(s4.x, ws, acc[ii*4+0]);
                acc[ii*4+1] = fmaf(s4.y, ws, acc[ii*4+1]);
                acc[ii*4+2] = fmaf(s4.z, ws, acc[ii*4+2]);
                acc[ii*4+3] = fmaf(s4.w, ws, acc[ii*4+3]);
            }
        }
    } else {
        const float* __restrict__ Wr = W + (size_t)(2 * (d - 1)) * CI * 64;
        const float* __restrict__ Ws = W + (size_t)(2 * d - 1) * CI * 64;
        for (int k = 0; k < CI; ++k) {
            const float wr = Wr[k * 64 + c];
            const float ws = Ws[k * 64 + c];
            #pragma unroll
            for (int ii = 0; ii < 4; ++ii) {
                const float4 s4 = *reinterpret_cast<const float4*>(&s_self[k][g * 16 + ii * 4]);
                const float4 r4 = *reinterpret_cast<const float4*>(&s_rel [k][g * 16 + ii * 4]);
                acc[ii*4+0] = fmaf(s4.x, ws, fmaf(r4.x, wr, acc[ii*4+0]));
                acc[ii*4+1] = fmaf(s4.y, ws, fmaf(r4.y, wr, acc[ii*4+1]));
                acc[ii*4+2] = fmaf(s4.z, ws, fmaf(r4.z, wr, acc[ii*4+2]));
                acc[ii*4+3] = fmaf(s4.w, ws, fmaf(r4.w, wr, acc[ii*4+3]));
            }
        }
    }

    const float gmv = bng[c], btv = bnb[c], mnv = bnm[c];
    const float rsv = rsqrtf(bnv[c] + 1e-3f);
    const float bias = (d == 0) ? B[20 * 64 + c]
                                : (B[(2 * (d - 1)) * 64 + c] + B[(2 * d - 1) * 64 + c]);
    #pragma unroll
    for (int i = 0; i < 16; ++i) {
        const int ai = g * 16 + i;
        if (ai < nA) {
            float v = fmaxf(acc[i] + bias, 0.f);
            v = (v - mnv) * rsv * gmv + btv;
            out[(size_t)(a0 + ai) * 64 + c] = v;
        }
    }
}

// ---------------------------------------------------------------------------
// Graph pool: p[a][c] = max(z[a][c], max_n z[adj[n]][c]); degree-0 passthrough.
// One wave per atom (64 channels).
// ---------------------------------------------------------------------------
__global__ __launch_bounds__(256) void pool_kernel(
    const float* __restrict__ z, AdjPtrs adj, float* __restrict__ p)
{
    const int t = threadIdx.x;
    const int a = blockIdx.x * 4 + (t >> 6);
    const int c = t & 63;
    if (a >= NATOMS) return;
    int d = 0;
    #pragma unroll
    for (int dd = 1; dd <= 10; ++dd) d += (a >= kStarts[dd]);
    float v = z[(size_t)a * 64 + c];
    if (d > 0) {
        const int j = a - kStarts[d];
        const int* __restrict__ ad = adj.p[d - 1];
        for (int n = 0; n < d; ++n) {
            const int idx = ad[(size_t)j * d + n];
            v = fmaxf(v, z[(size_t)idx * 64 + c]);
        }
    }
    p[(size_t)a * 64 + c] = v;
}

// ---------------------------------------------------------------------------
// Dense 64->128 + ReLU + BN2, fused into segment sum/max via atomics.
// Block = 2 atoms x 128 channels.
// ---------------------------------------------------------------------------
__global__ __launch_bounds__(256) void dense_seg_kernel(
    const float* __restrict__ p, const float* __restrict__ Wd, const float* __restrict__ bd,
    const float* __restrict__ bng, const float* __restrict__ bnb,
    const float* __restrict__ bnm, const float* __restrict__ bnv,
    const int* __restrict__ mem,
    float* __restrict__ segS, unsigned* __restrict__ segM)
{
    __shared__ float sm[2][64];
    const int t = threadIdx.x;
    const int a0 = blockIdx.x * 2;
    for (int e = t; e < 128; e += 256) {
        const int ai = e >> 6, k = e & 63;
        if (a0 + ai < NATOMS) sm[ai][k] = p[(size_t)(a0 + ai) * 64 + k];
    }
    __syncthreads();
    const int al = t >> 7, c = t & 127;
    const int a = a0 + al;
    if (a < NATOMS) {
        float acc = bd[c];
        #pragma unroll 8
        for (int k = 0; k < 64; ++k) acc = fmaf(sm[al][k], Wd[k * 128 + c], acc);
        float v = fmaxf(acc, 0.f);
        v = (v - bnm[c]) * rsqrtf(bnv[c] + 1e-3f) * bng[c] + bnb[c];
        const int m = mem[a];
        atomicAdd(&segS[(size_t)m * 128 + c], v);
        atomicMax(&segM[(size_t)m * 128 + c], enc_f32(v));
    }
}

__global__ void seg_init_kernel(float* __restrict__ segS, unsigned* __restrict__ segM)
{
    const int n = NBATCH * 128;
    for (int i = blockIdx.x * blockDim.x + threadIdx.x; i < n; i += gridDim.x * blockDim.x) {
        segS[i] = 0.f;
        segM[i] = 0x007FFFFFu; // enc(-inf)
    }
}

__global__ void nf_kernel(const float* __restrict__ segS, const unsigned* __restrict__ segM,
                          float* __restrict__ nf)
{
    const int i = blockIdx.x * blockDim.x + threadIdx.x; // < NBATCH*128
    const int m = i >> 7, c = i & 127;
    nf[(size_t)m * 256 + c]       = tanhf(segS[i]);
    nf[(size_t)m * 256 + 128 + c] = tanhf(dec_f32(segM[i]));
}

// fd0: h = relu(nf @ W + b), 32768x256 @ 256x256. 64x64 tile per block.
__global__ __launch_bounds__(256) void fd0_kernel(
    const float* __restrict__ nf, const float* __restrict__ W, const float* __restrict__ b,
    float* __restrict__ h)
{
    __shared__ __align__(16) float sx[256][64];
    const int t = threadIdx.x;
    const int r0 = (blockIdx.x >> 2) * 64;
    const int c0 = (blockIdx.x & 3) * 64;
    for (int e = t; e < 64 * 256; e += 256) {
        const int ri = e >> 8, k = e & 255;
        sx[k][ri] = nf[(size_t)(r0 + ri) * 256 + k];
    }
    __syncthreads();
    const int c = t & 63, g = t >> 6;
    float acc[16];
    #pragma unroll
    for (int i = 0; i < 16; ++i) acc[i] = 0.f;
    for (int k = 0; k < 256; ++k) {
        const float w = W[(size_t)k * 256 + c0 + c];
        #pragma unroll
        for (int ii = 0; ii < 4; ++ii) {
            const float4 v = *reinterpret_cast<const float4*>(&sx[k][g * 16 + ii * 4]);
            acc[ii*4+0] = fmaf(v.x, w, acc[ii*4+0]);
            acc[ii*4+1] = fmaf(v.y, w, acc[ii*4+1]);
            acc[ii*4+2] = fmaf(v.z, w, acc[ii*4+2]);
            acc[ii*4+3] = fmaf(v.w, w, acc[ii*4+3]);
        }
    }
    const float bb = b[c0 + c];
    #pragma unroll
    for (int i = 0; i < 16; ++i)
        h[(size_t)(r0 + g * 16 + i) * 256 + c0 + c] = fmaxf(acc[i] + bb, 0.f);
}

// rd: logits = h @ W + b (256->24), then pairwise softmax. 32 rows x 12 pairs.
__global__ __launch_bounds__(384) void rd_kernel(
    const float* __restrict__ h, const float* __restrict__ W, const float* __restrict__ b,
    float* __restrict__ outP, float* __restrict__ outL)
{
    __shared__ float sh[32][257];
    const int t = threadIdx.x;
    const int r0 = blockIdx.x * 32;
    for (int e = t; e < 32 * 256; e += 384) {
        const int ri = e >> 8, k = e & 255;
        sh[ri][k] = h[(size_t)(r0 + ri) * 256 + k];
    }
    __syncthreads();
    const int r = t / 12, pj = t % 12;
    float a0 = b[2 * pj], a1 = b[2 * pj + 1];
    for (int k = 0; k < 256; ++k) {
        const float hv = sh[r][k];
        a0 = fmaf(hv, W[k * 24 + 2 * pj],     a0);
        a1 = fmaf(hv, W[k * 24 + 2 * pj + 1], a1);
    }
    const size_t m = (size_t)(r0 + r);
    outL[m * 24 + 2 * pj]     = a0;
    outL[m * 24 + 2 * pj + 1] = a1;
    const float mx = fmaxf(a0, a1);
    const float e0 = expf(a0 - mx), e1 = expf(a1 - mx);
    const float inv = 1.f / (e0 + e1);
    outP[m * 24 + 2 * pj]     = e0 * inv;
    outP[m * 24 + 2 * pj + 1] = e1 * inv;
}

} // namespace

extern "C" void kernel_launch(void* const* d_in, const int* in_sizes, int n_in,
                              void* d_out, int out_size, void* d_ws, size_t ws_size,
                              hipStream_t stream)
{
    const float* x       = (const float*)d_in[0];
    const int*   mem     = (const int*)d_in[2];
    AdjPtrs adj;
    for (int d = 0; d < 10; ++d) adj.p[d] = (const int*)d_in[4 + d];
    const float* gc0_W = (const float*)d_in[14];
    const float* gc0_b = (const float*)d_in[15];
    const float* gc1_W = (const float*)d_in[16];
    const float* gc1_b = (const float*)d_in[17];
    const float* bn0g = (const float*)d_in[18], *bn0b = (const float*)d_in[19];
    const float* bn0m = (const float*)d_in[20], *bn0v = (const float*)d_in[21];
    const float* bn1g = (const float*)d_in[22], *bn1b = (const float*)d_in[23];
    const float* bn1m = (const float*)d_in[24], *bn1v = (const float*)d_in[25];
    const float* bn2g = (const float*)d_in[26], *bn2b = (const float*)d_in[27];
    const float* bn2m = (const float*)d_in[28], *bn2v = (const float*)d_in[29];
    const float* dW   = (const float*)d_in[30], *db   = (const float*)d_in[31];
    const float* fW   = (const float*)d_in[32], *fb   = (const float*)d_in[33];
    const float* rW   = (const float*)d_in[34], *rb   = (const float*)d_in[35];

    float*    zbuf = (float*)d_ws;
    float*    pbuf = zbuf + (size_t)NATOMS * 64;
    float*    segS = pbuf + (size_t)NATOMS * 64;
    unsigned* segM = (unsigned*)(segS + (size_t)NBATCH * 128);
    float*    hbuf = (float*)(segM + (size_t)NBATCH * 128);

    float* outP = (float*)d_out;
    float* outL = outP + (size_t)NBATCH * 24;
    float* nfb  = outL + (size_t)NBATCH * 24;

    int convBlocks = 0;
    for (int d = 0; d <= 10; ++d) convBlocks += (kCounts[d] + 63) >> 6;

    seg_init_kernel<<<4096, 256, 0, stream>>>(segS, segM);

    // layer 1: conv(75->64)+relu+bn0 -> pool
    conv_kernel<75><<<convBlocks, 256, 0, stream>>>(x, adj, gc0_W, gc0_b,
                                                    bn0g, bn0b, bn0m, bn0v, zbuf);
    pool_kernel<<<(NATOMS + 3) / 4, 256, 0, stream>>>(zbuf, adj, pbuf);

    // layer 2: conv(64->64)+relu+bn1 -> pool
    conv_kernel<64><<<convBlocks, 256, 0, stream>>>(pbuf, adj, gc1_W, gc1_b,
                                                    bn1g, bn1b, bn1m, bn1v, zbuf);
    pool_kernel<<<(NATOMS + 3) / 4, 256, 0, stream>>>(zbuf, adj, pbuf);

    // dense+relu+bn2 fused with segment sum/max
    dense_seg_kernel<<<(NATOMS + 1) / 2, 256, 0, stream>>>(pbuf, dW, db,
                                                           bn2g, bn2b, bn2m, bn2v,
                                                           mem, segS, segM);
    // nf = tanh(concat(sum, max))
    nf_kernel<<<(NBATCH * 128) / 256, 256, 0, stream>>>(segS, segM, nfb);
    // h = relu(nf @ fd0_W + fd0_b)
    fd0_kernel<<<(NBATCH / 64) * 4, 256, 0, stream>>>(nfb, fW, fb, hbuf);
    // logits + softmax
    rd_kernel<<<NBATCH / 32, 384, 0, stream>>>(hbuf, rW, rb, outP, outL);
}

// Round 2
// 2840.184 us; speedup vs baseline: 1.2523x; 1.2523x over previous
//
#include <hip/hip_runtime.h>
#include <math.h>

namespace {

constexpr int NATOMS = 1000000;
constexpr int NBATCH = 32768;
constexpr int kCounts[11] = {10000,250000,300000,250000,120000,40000,15000,8000,4000,2000,1000};
constexpr int kStarts[11] = {0,10000,260000,560000,810000,930000,970000,985000,993000,997000,999000};

struct AdjPtrs { const int* p[10]; };

// ---------------------------------------------------------------------------
// Graph conv + ReLU + BN.  One block = 64 atoms of a single degree.
// LDS holds self rows and neighbor-sum rows, k-major [CI][64].
// Thread (c = t&63, g = t>>6) computes out[g*16+i][c], i in 0..15.
// ---------------------------------------------------------------------------
template<int CI>
__global__ __launch_bounds__(256) void conv_kernel(
    const float* __restrict__ x, AdjPtrs adj,
    const float* __restrict__ W, const float* __restrict__ B,
    const float* __restrict__ bng, const float* __restrict__ bnb,
    const float* __restrict__ bnm, const float* __restrict__ bnv,
    float* __restrict__ out)
{
    __shared__ __align__(16) float s_self[CI][64];
    __shared__ __align__(16) float s_rel[CI][64];

    int d = 0, rem = blockIdx.x;
    for (;;) { int nb = (kCounts[d] + 63) >> 6; if (rem < nb) break; rem -= nb; ++d; }
    const int j0 = rem << 6;
    const int nA = min(64, kCounts[d] - j0);
    const int a0 = kStarts[d] + j0;
    const int t = threadIdx.x;

    // stage self rows (contiguous global region -> transposed LDS)
    for (int e = t; e < nA * CI; e += 256) {
        int ai = e / CI, k = e - ai * CI;
        s_self[k][ai] = x[(size_t)(a0 + ai) * CI + k];
    }

    // stage neighbor-sum rows: 4 threads per atom accumulate in registers
    if (d > 0) {
        constexpr int NQ = (CI + 3) / 4;
        const int ai = t >> 2, g4 = t & 3;
        if (ai < nA) {
            float r[NQ];
            #pragma unroll
            for (int q = 0; q < NQ; ++q) r[q] = 0.f;
            const int* __restrict__ ad = adj.p[d - 1];
            for (int n = 0; n < d; ++n) {
                const int idx = ad[(size_t)(j0 + ai) * d + n];
                const float* __restrict__ xr = x + (size_t)idx * CI;
                #pragma unroll
                for (int q = 0; q < NQ; ++q) {
                    const int e = g4 + 4 * q;
                    if (e < CI) r[q] += xr[e];
                }
            }
            #pragma unroll
            for (int q = 0; q < NQ; ++q) {
                const int e = g4 + 4 * q;
                if (e < CI) s_rel[e][ai] = r[q];
            }
        }
    }
    __syncthreads();

    const int c = t & 63, g = t >> 6;
    float acc[16];
    #pragma unroll
    for (int i = 0; i < 16; ++i) acc[i] = 0.f;

    if (d == 0) {
        const float* __restrict__ Ws = W + (size_t)(2 * 10) * CI * 64;
        for (int k = 0; k < CI; ++k) {
            const float ws = Ws[k * 64 + c];
            #pragma unroll
            for (int ii = 0; ii < 4; ++ii) {
                const float4 s4 = *reinterpret_cast<const float4*>(&s_self[k][g * 16 + ii * 4]);
                acc[ii*4+0] = fmaf(s4.x, ws, acc[ii*4+0]);
                acc[ii*4+1] = fmaf(s4.y, ws, acc[ii*4+1]);
                acc[ii*4+2] = fmaf(s4.z, ws, acc[ii*4+2]);
                acc[ii*4+3] = fmaf(s4.w, ws, acc[ii*4+3]);
            }
        }
    } else {
        const float* __restrict__ Wr = W + (size_t)(2 * (d - 1)) * CI * 64;
        const float* __restrict__ Ws = W + (size_t)(2 * d - 1) * CI * 64;
        for (int k = 0; k < CI; ++k) {
            const float wr = Wr[k * 64 + c];
            const float ws = Ws[k * 64 + c];
            #pragma unroll
            for (int ii = 0; ii < 4; ++ii) {
                const float4 s4 = *reinterpret_cast<const float4*>(&s_self[k][g * 16 + ii * 4]);
                const float4 r4 = *reinterpret_cast<const float4*>(&s_rel [k][g * 16 + ii * 4]);
                acc[ii*4+0] = fmaf(s4.x, ws, fmaf(r4.x, wr, acc[ii*4+0]));
                acc[ii*4+1] = fmaf(s4.y, ws, fmaf(r4.y, wr, acc[ii*4+1]));
                acc[ii*4+2] = fmaf(s4.z, ws, fmaf(r4.z, wr, acc[ii*4+2]));
                acc[ii*4+3] = fmaf(s4.w, ws, fmaf(r4.w, wr, acc[ii*4+3]));
            }
        }
    }

    const float gmv = bng[c], btv = bnb[c], mnv = bnm[c];
    const float rsv = rsqrtf(bnv[c] + 1e-3f);
    const float bias = (d == 0) ? B[20 * 64 + c]
                                : (B[(2 * (d - 1)) * 64 + c] + B[(2 * d - 1) * 64 + c]);
    #pragma unroll
    for (int i = 0; i < 16; ++i) {
        const int ai = g * 16 + i;
        if (ai < nA) {
            float v = fmaxf(acc[i] + bias, 0.f);
            v = (v - mnv) * rsv * gmv + btv;
            out[(size_t)(a0 + ai) * 64 + c] = v;
        }
    }
}

// ---------------------------------------------------------------------------
// Graph pool: p[a][c] = max(z[a][c], max_n z[adj[n]][c]); degree-0 passthrough.
// One wave per atom (64 channels).
// ---------------------------------------------------------------------------
__global__ __launch_bounds__(256) void pool_kernel(
    const float* __restrict__ z, AdjPtrs adj, float* __restrict__ p)
{
    const int t = threadIdx.x;
    const int a = blockIdx.x * 4 + (t >> 6);
    const int c = t & 63;
    if (a >= NATOMS) return;
    int d = 0;
    #pragma unroll
    for (int dd = 1; dd <= 10; ++dd) d += (a >= kStarts[dd]);
    float v = z[(size_t)a * 64 + c];
    if (d > 0) {
        const int j = a - kStarts[d];
        const int* __restrict__ ad = adj.p[d - 1];
        for (int n = 0; n < d; ++n) {
            const int idx = ad[(size_t)j * d + n];
            v = fmaxf(v, z[(size_t)idx * 64 + c]);
        }
    }
    p[(size_t)a * 64 + c] = v;
}

// ---------------------------------------------------------------------------
// Counting sort by membership: hist -> scan -> scatter.
// ---------------------------------------------------------------------------
__global__ __launch_bounds__(256) void hist_kernel(const int* __restrict__ mem,
                                                   int* __restrict__ cnt)
{
    const int a = blockIdx.x * 256 + threadIdx.x;
    if (a < NATOMS) atomicAdd(&cnt[mem[a]], 1);
}

__global__ __launch_bounds__(512) void scan_kernel(const int* __restrict__ cnt,
                                                   int* __restrict__ off,
                                                   int* __restrict__ cur)
{
    __shared__ int part[512];
    const int t = threadIdx.x;
    const int base = t * 64;
    int s = 0;
    #pragma unroll 8
    for (int i = 0; i < 64; ++i) s += cnt[base + i];
    part[t] = s;
    __syncthreads();
    for (int o = 1; o < 512; o <<= 1) {
        int v = (t >= o) ? part[t - o] : 0;
        __syncthreads();
        part[t] += v;
        __syncthreads();
    }
    int run = (t == 0) ? 0 : part[t - 1];
    for (int i = 0; i < 64; ++i) {
        off[base + i] = run;
        cur[base + i] = run;
        run += cnt[base + i];
    }
}

__global__ __launch_bounds__(256) void scatter_kernel(const int* __restrict__ mem,
                                                      int* __restrict__ cur,
                                                      int* __restrict__ sorted)
{
    const int a = blockIdx.x * 256 + threadIdx.x;
    if (a < NATOMS) {
        const int pos = atomicAdd(&cur[mem[a]], 1);
        sorted[pos] = a;
    }
}

// ---------------------------------------------------------------------------
// Per-segment: dense 64->128 + ReLU + BN2, reduce (sum,max) over the segment's
// atoms in registers, write nf = tanh(concat(sum,max)) directly.
// One block of 128 threads per segment; thread c owns channel c and keeps
// dense_W[:,c] in 64 VGPRs.
// ---------------------------------------------------------------------------
__global__ __launch_bounds__(128) void seg_reduce_kernel(
    const float* __restrict__ p,
    const int* __restrict__ sorted, const int* __restrict__ off,
    const int* __restrict__ cnt,
    const float* __restrict__ Wd, const float* __restrict__ bd,
    const float* __restrict__ bng, const float* __restrict__ bnb,
    const float* __restrict__ bnm, const float* __restrict__ bnv,
    float* __restrict__ nf)
{
    __shared__ __align__(16) float rows[4][64];
    const int m = blockIdx.x;
    const int c = threadIdx.x;

    float wcol[64];
    #pragma unroll
    for (int k = 0; k < 64; ++k) wcol[k] = Wd[k * 128 + c];

    const float bias = bd[c];
    const float gmv = bng[c], btv = bnb[c], mnv = bnm[c];
    const float rsv = rsqrtf(bnv[c] + 1e-3f);

    const int n = cnt[m];
    const int start = off[m];

    float s = 0.f, mx = -INFINITY;
    for (int base = 0; base < n; base += 4) {
        const int take = min(4, n - base);
        __syncthreads();
        for (int e = c; e < take * 64; e += 128) {
            const int r = e >> 6, k = e & 63;
            rows[r][k] = p[(size_t)sorted[start + base + r] * 64 + k];
        }
        __syncthreads();
        for (int r = 0; r < take; ++r) {
            float acc = bias;
            #pragma unroll
            for (int k = 0; k < 64; ++k) acc = fmaf(rows[r][k], wcol[k], acc);
            float v = fmaxf(acc, 0.f);
            v = (v - mnv) * rsv * gmv + btv;
            s += v;
            mx = fmaxf(mx, v);
        }
    }
    nf[(size_t)m * 256 + c]       = tanhf(s);
    nf[(size_t)m * 256 + 128 + c] = tanhf(mx);   // tanh(-inf) = -1 for empty
}

// fd0: h = relu(nf @ W + b), 32768x256 @ 256x256. 64x64 tile per block.
__global__ __launch_bounds__(256) void fd0_kernel(
    const float* __restrict__ nf, const float* __restrict__ W, const float* __restrict__ b,
    float* __restrict__ h)
{
    __shared__ __align__(16) float sx[256][64];
    const int t = threadIdx.x;
    const int r0 = (blockIdx.x >> 2) * 64;
    const int c0 = (blockIdx.x & 3) * 64;
    for (int e = t; e < 64 * 256; e += 256) {
        const int ri = e >> 8, k = e & 255;
        sx[k][ri] = nf[(size_t)(r0 + ri) * 256 + k];
    }
    __syncthreads();
    const int c = t & 63, g = t >> 6;
    float acc[16];
    #pragma unroll
    for (int i = 0; i < 16; ++i) acc[i] = 0.f;
    for (int k = 0; k < 256; ++k) {
        const float w = W[(size_t)k * 256 + c0 + c];
        #pragma unroll
        for (int ii = 0; ii < 4; ++ii) {
            const float4 v = *reinterpret_cast<const float4*>(&sx[k][g * 16 + ii * 4]);
            acc[ii*4+0] = fmaf(v.x, w, acc[ii*4+0]);
            acc[ii*4+1] = fmaf(v.y, w, acc[ii*4+1]);
            acc[ii*4+2] = fmaf(v.z, w, acc[ii*4+2]);
            acc[ii*4+3] = fmaf(v.w, w, acc[ii*4+3]);
        }
    }
    const float bb = b[c0 + c];
    #pragma unroll
    for (int i = 0; i < 16; ++i)
        h[(size_t)(r0 + g * 16 + i) * 256 + c0 + c] = fmaxf(acc[i] + bb, 0.f);
}

// rd: logits = h @ W + b (256->24), then pairwise softmax. 32 rows x 12 pairs.
__global__ __launch_bounds__(384) void rd_kernel(
    const float* __restrict__ h, const float* __restrict__ W, const float* __restrict__ b,
    float* __restrict__ outP, float* __restrict__ outL)
{
    __shared__ float sh[32][257];
    const int t = threadIdx.x;
    const int r0 = blockIdx.x * 32;
    for (int e = t; e < 32 * 256; e += 384) {
        const int ri = e >> 8, k = e & 255;
        sh[ri][k] = h[(size_t)(r0 + ri) * 256 + k];
    }
    __syncthreads();
    const int r = t / 12, pj = t % 12;
    float a0 = b[2 * pj], a1 = b[2 * pj + 1];
    for (int k = 0; k < 256; ++k) {
        const float hv = sh[r][k];
        a0 = fmaf(hv, W[k * 24 + 2 * pj],     a0);
        a1 = fmaf(hv, W[k * 24 + 2 * pj + 1], a1);
    }
    const size_t m = (size_t)(r0 + r);
    outL[m * 24 + 2 * pj]     = a0;
    outL[m * 24 + 2 * pj + 1] = a1;
    const float mx = fmaxf(a0, a1);
    const float e0 = expf(a0 - mx), e1 = expf(a1 - mx);
    const float inv = 1.f / (e0 + e1);
    outP[m * 24 + 2 * pj]     = e0 * inv;
    outP[m * 24 + 2 * pj + 1] = e1 * inv;
}

} // namespace

extern "C" void kernel_launch(void* const* d_in, const int* in_sizes, int n_in,
                              void* d_out, int out_size, void* d_ws, size_t ws_size,
                              hipStream_t stream)
{
    const float* x       = (const float*)d_in[0];
    const int*   mem     = (const int*)d_in[2];
    AdjPtrs adj;
    for (int d = 0; d < 10; ++d) adj.p[d] = (const int*)d_in[4 + d];
    const float* gc0_W = (const float*)d_in[14];
    const float* gc0_b = (const float*)d_in[15];
    const float* gc1_W = (const float*)d_in[16];
    const float* gc1_b = (const float*)d_in[17];
    const float* bn0g = (const float*)d_in[18], *bn0b = (const float*)d_in[19];
    const float* bn0m = (const float*)d_in[20], *bn0v = (const float*)d_in[21];
    const float* bn1g = (const float*)d_in[22], *bn1b = (const float*)d_in[23];
    const float* bn1m = (const float*)d_in[24], *bn1v = (const float*)d_in[25];
    const float* bn2g = (const float*)d_in[26], *bn2b = (const float*)d_in[27];
    const float* bn2m = (const float*)d_in[28], *bn2v = (const float*)d_in[29];
    const float* dW   = (const float*)d_in[30], *db   = (const float*)d_in[31];
    const float* fW   = (const float*)d_in[32], *fb   = (const float*)d_in[33];
    const float* rW   = (const float*)d_in[34], *rb   = (const float*)d_in[35];

    float* zbuf = (float*)d_ws;
    float* pbuf = zbuf + (size_t)NATOMS * 64;
    float* hbuf = pbuf + (size_t)NATOMS * 64;
    int*   cnt    = (int*)(hbuf + (size_t)NBATCH * 256);
    int*   offp   = cnt + NBATCH;
    int*   cur    = offp + NBATCH;
    int*   sorted = cur + NBATCH;

    float* outP = (float*)d_out;
    float* outL = outP + (size_t)NBATCH * 24;
    float* nfb  = outL + (size_t)NBATCH * 24;

    int convBlocks = 0;
    for (int d = 0; d <= 10; ++d) convBlocks += (kCounts[d] + 63) >> 6;

    // counting sort by membership (independent of conv path)
    hipMemsetAsync(cnt, 0, NBATCH * sizeof(int), stream);
    hist_kernel<<<(NATOMS + 255) / 256, 256, 0, stream>>>(mem, cnt);
    scan_kernel<<<1, 512, 0, stream>>>(cnt, offp, cur);
    scatter_kernel<<<(NATOMS + 255) / 256, 256, 0, stream>>>(mem, cur, sorted);

    // layer 1: conv(75->64)+relu+bn0 -> pool
    conv_kernel<75><<<convBlocks, 256, 0, stream>>>(x, adj, gc0_W, gc0_b,
                                                    bn0g, bn0b, bn0m, bn0v, zbuf);
    pool_kernel<<<(NATOMS + 3) / 4, 256, 0, stream>>>(zbuf, adj, pbuf);

    // layer 2: conv(64->64)+relu+bn1 -> pool
    conv_kernel<64><<<convBlocks, 256, 0, stream>>>(pbuf, adj, gc1_W, gc1_b,
                                                    bn1g, bn1b, bn1m, bn1v, zbuf);
    pool_kernel<<<(NATOMS + 3) / 4, 256, 0, stream>>>(zbuf, adj, pbuf);

    // per-segment dense+relu+bn2 + sum/max reduce + tanh -> nf
    seg_reduce_kernel<<<NBATCH, 128, 0, stream>>>(pbuf, sorted, offp, cnt,
                                                  dW, db, bn2g, bn2b, bn2m, bn2v, nfb);
    // h = relu(nf @ fd0_W + fd0_b)
    fd0_kernel<<<(NBATCH / 64) * 4, 256, 0, stream>>>(nfb, fW, fb, hbuf);
    // logits + softmax
    rd_kernel<<<NBATCH / 32, 384, 0, stream>>>(hbuf, rW, rb, outP, outL);
}

// Round 3
// 2585.322 us; speedup vs baseline: 1.3758x; 1.0986x over previous
//
#include <hip/hip_runtime.h>
#include <math.h>

namespace {

constexpr int NATOMS = 1000000;
constexpr int NBATCH = 32768;
constexpr int kCounts[11] = {10000,250000,300000,250000,120000,40000,15000,8000,4000,2000,1000};
constexpr int kStarts[11] = {0,10000,260000,560000,810000,930000,970000,985000,993000,997000,999000};

// swizzled column: xor bits 2-5 of the atom index with (k&15) -- keeps float4
// groups contiguous, makes transposed staging writes conflict-free, and the
// compute-side reads are wave-uniform broadcasts (conflict-free regardless).
__device__ __forceinline__ int swz(int ai, int k) { return ai ^ ((k & 15) << 2); }

// ---------------------------------------------------------------------------
// Degree-0 conv: out = relu(x @ W[20] + b[20]) -> BN.  64 atoms per block.
// ---------------------------------------------------------------------------
template<int CI>
__global__ __launch_bounds__(256) void conv0_kernel(
    const float* __restrict__ x, int count, int start,
    const float* __restrict__ W, const float* __restrict__ B,
    const float* __restrict__ bng, const float* __restrict__ bnb,
    const float* __restrict__ bnm, const float* __restrict__ bnv,
    float* __restrict__ out)
{
    __shared__ __align__(16) float s_self[CI][64];
    const int j0 = blockIdx.x << 6;
    const int nA = min(64, count - j0);
    const int a0 = start + j0;
    const int t = threadIdx.x;

    for (int e = t; e < nA * CI; e += 256) {
        const int ai = e / CI, k = e - ai * CI;
        s_self[k][swz(ai, k)] = x[(size_t)(a0 + ai) * CI + k];
    }
    __syncthreads();

    const int c = t & 63, g = t >> 6;
    float acc[16];
    #pragma unroll
    for (int i = 0; i < 16; ++i) acc[i] = 0.f;

    const float* __restrict__ Ws = W + (size_t)(2 * 10) * CI * 64;
    for (int k = 0; k < CI; ++k) {
        const int sw = (k & 15) << 2;
        const float ws = Ws[k * 64 + c];
        #pragma unroll
        for (int ii = 0; ii < 4; ++ii) {
            const float4 s4 = *reinterpret_cast<const float4*>(&s_self[k][(g * 16 + ii * 4) ^ sw]);
            acc[ii*4+0] = fmaf(s4.x, ws, acc[ii*4+0]);
            acc[ii*4+1] = fmaf(s4.y, ws, acc[ii*4+1]);
            acc[ii*4+2] = fmaf(s4.z, ws, acc[ii*4+2]);
            acc[ii*4+3] = fmaf(s4.w, ws, acc[ii*4+3]);
        }
    }

    const float gmv = bng[c], btv = bnb[c], mnv = bnm[c];
    const float rsv = rsqrtf(bnv[c] + 1e-3f);
    const float bias = B[20 * 64 + c];
    #pragma unroll
    for (int i = 0; i < 16; ++i) {
        const int ai = g * 16 + i;
        if (ai < nA) {
            float v = fmaxf(acc[i] + bias, 0.f);
            v = (v - mnv) * rsv * gmv + btv;
            out[(size_t)(a0 + ai) * 64 + c] = v;
        }
    }
}

// ---------------------------------------------------------------------------
// Degree-D conv (D>=1), templated: indices prefetched, gather unrolled.
// ---------------------------------------------------------------------------
template<int CI, int D>
__global__ __launch_bounds__(256) void conv_kernel(
    const float* __restrict__ x, const int* __restrict__ ad, int count, int start,
    const float* __restrict__ W, const float* __restrict__ B,
    const float* __restrict__ bng, const float* __restrict__ bnb,
    const float* __restrict__ bnm, const float* __restrict__ bnv,
    float* __restrict__ out)
{
    __shared__ __align__(16) float s_self[CI][64];
    __shared__ __align__(16) float s_rel[CI][64];

    const int j0 = blockIdx.x << 6;
    const int nA = min(64, count - j0);
    const int a0 = start + j0;
    const int t = threadIdx.x;

    // ---- stage self rows ----
    if constexpr (CI == 64) {
        for (int v = t; v < nA * 16; v += 256) {
            const int ai = v >> 4, k0 = (v & 15) * 4;
            const float4 r = *reinterpret_cast<const float4*>(x + (size_t)(a0 + ai) * 64 + k0);
            s_self[k0 + 0][swz(ai, k0 + 0)] = r.x;
            s_self[k0 + 1][swz(ai, k0 + 1)] = r.y;
            s_self[k0 + 2][swz(ai, k0 + 2)] = r.z;
            s_self[k0 + 3][swz(ai, k0 + 3)] = r.w;
        }
    } else {
        for (int e = t; e < nA * CI; e += 256) {
            const int ai = e / CI, k = e - ai * CI;
            s_self[k][swz(ai, k)] = x[(size_t)(a0 + ai) * CI + k];
        }
    }

    // ---- stage neighbor sums: 4 lanes per atom, indices prefetched ----
    {
        const int ai = t >> 2, g4 = t & 3;
        if (ai < nA) {
            int idxs[D];
            #pragma unroll
            for (int n = 0; n < D; ++n) idxs[n] = ad[(size_t)(j0 + ai) * D + n];

            if constexpr (CI == 64) {
                float4 r[4];
                #pragma unroll
                for (int q = 0; q < 4; ++q) r[q] = make_float4(0.f, 0.f, 0.f, 0.f);
                for (int n = 0; n < D; ++n) {
                    const float4* __restrict__ xr = reinterpret_cast<const float4*>(x + (size_t)idxs[n] * 64);
                    #pragma unroll
                    for (int q = 0; q < 4; ++q) {
                        const float4 v = xr[g4 + 4 * q];
                        r[q].x += v.x; r[q].y += v.y; r[q].z += v.z; r[q].w += v.w;
                    }
                }
                #pragma unroll
                for (int q = 0; q < 4; ++q) {
                    const int k0 = (g4 + 4 * q) * 4;
                    s_rel[k0 + 0][swz(ai, k0 + 0)] = r[q].x;
                    s_rel[k0 + 1][swz(ai, k0 + 1)] = r[q].y;
                    s_rel[k0 + 2][swz(ai, k0 + 2)] = r[q].z;
                    s_rel[k0 + 3][swz(ai, k0 + 3)] = r[q].w;
                }
            } else {
                constexpr int NQ = (CI + 3) / 4;
                float r[NQ];
                #pragma unroll
                for (int q = 0; q < NQ; ++q) r[q] = 0.f;
                for (int n = 0; n < D; ++n) {
                    const float* __restrict__ xr = x + (size_t)idxs[n] * CI;
                    #pragma unroll
                    for (int q = 0; q < NQ; ++q) {
                        const int e = g4 + 4 * q;
                        if (e < CI) r[q] += xr[e];
                    }
                }
                #pragma unroll
                for (int q = 0; q < NQ; ++q) {
                    const int e = g4 + 4 * q;
                    if (e < CI) s_rel[e][swz(ai, e)] = r[q];
                }
            }
        }
    }
    __syncthreads();

    const int c = t & 63, g = t >> 6;
    float acc[16];
    #pragma unroll
    for (int i = 0; i < 16; ++i) acc[i] = 0.f;

    const float* __restrict__ Wr = W + (size_t)(2 * (D - 1)) * CI * 64;
    const float* __restrict__ Ws = W + (size_t)(2 * D - 1) * CI * 64;
    for (int k = 0; k < CI; ++k) {
        const int sw = (k & 15) << 2;
        const float wr = Wr[k * 64 + c];
        const float ws = Ws[k * 64 + c];
        #pragma unroll
        for (int ii = 0; ii < 4; ++ii) {
            const int col = (g * 16 + ii * 4) ^ sw;
            const float4 s4 = *reinterpret_cast<const float4*>(&s_self[k][col]);
            const float4 r4 = *reinterpret_cast<const float4*>(&s_rel [k][col]);
            acc[ii*4+0] = fmaf(s4.x, ws, fmaf(r4.x, wr, acc[ii*4+0]));
            acc[ii*4+1] = fmaf(s4.y, ws, fmaf(r4.y, wr, acc[ii*4+1]));
            acc[ii*4+2] = fmaf(s4.z, ws, fmaf(r4.z, wr, acc[ii*4+2]));
            acc[ii*4+3] = fmaf(s4.w, ws, fmaf(r4.w, wr, acc[ii*4+3]));
        }
    }

    const float gmv = bng[c], btv = bnb[c], mnv = bnm[c];
    const float rsv = rsqrtf(bnv[c] + 1e-3f);
    const float bias = B[(2 * (D - 1)) * 64 + c] + B[(2 * D - 1) * 64 + c];
    #pragma unroll
    for (int i = 0; i < 16; ++i) {
        const int ai = g * 16 + i;
        if (ai < nA) {
            float v = fmaxf(acc[i] + bias, 0.f);
            v = (v - mnv) * rsv * gmv + btv;
            out[(size_t)(a0 + ai) * 64 + c] = v;
        }
    }
}

// ---------------------------------------------------------------------------
// Graph pool, templated by degree. 4 atoms per 256-thread block; lane=channel.
// ---------------------------------------------------------------------------
template<int D>
__global__ __launch_bounds__(256) void pool_kernel(
    const float* __restrict__ z, const int* __restrict__ ad, int count, int start,
    float* __restrict__ p)
{
    const int t = threadIdx.x;
    const int j = blockIdx.x * 4 + (t >> 6);
    if (j >= count) return;
    const int c = t & 63;
    const int a = start + j;
    float v = z[(size_t)a * 64 + c];
    int idxs[D];
    #pragma unroll
    for (int n = 0; n < D; ++n) idxs[n] = ad[(size_t)j * D + n];
    #pragma unroll
    for (int n = 0; n < D; ++n) v = fmaxf(v, z[(size_t)idxs[n] * 64 + c]);
    p[(size_t)a * 64 + c] = v;
}

// degree-0 passthrough: copy first 10000 atom rows (float4)
__global__ __launch_bounds__(256) void copy0_kernel(const float* __restrict__ z,
                                                    float* __restrict__ p)
{
    const int n4 = kCounts[0] * 16;
    for (int i = blockIdx.x * 256 + threadIdx.x; i < n4; i += gridDim.x * 256)
        reinterpret_cast<float4*>(p)[i] = reinterpret_cast<const float4*>(z)[i];
}

// ---------------------------------------------------------------------------
// Counting sort by membership: hist -> scan -> scatter.
// ---------------------------------------------------------------------------
__global__ __launch_bounds__(256) void hist_kernel(const int* __restrict__ mem,
                                                   int* __restrict__ cnt)
{
    const int a = blockIdx.x * 256 + threadIdx.x;
    if (a < NATOMS) atomicAdd(&cnt[mem[a]], 1);
}

__global__ __launch_bounds__(512) void scan_kernel(const int* __restrict__ cnt,
                                                   int* __restrict__ off,
                                                   int* __restrict__ cur)
{
    __shared__ int part[512];
    const int t = threadIdx.x;
    const int base = t * 64;
    int s = 0;
    #pragma unroll 8
    for (int i = 0; i < 64; ++i) s += cnt[base + i];
    part[t] = s;
    __syncthreads();
    for (int o = 1; o < 512; o <<= 1) {
        int v = (t >= o) ? part[t - o] : 0;
        __syncthreads();
        part[t] += v;
        __syncthreads();
    }
    int run = (t == 0) ? 0 : part[t - 1];
    for (int i = 0; i < 64; ++i) {
        off[base + i] = run;
        cur[base + i] = run;
        run += cnt[base + i];
    }
}

__global__ __launch_bounds__(256) void scatter_kernel(const int* __restrict__ mem,
                                                      int* __restrict__ cur,
                                                      int* __restrict__ sorted)
{
    const int a = blockIdx.x * 256 + threadIdx.x;
    if (a < NATOMS) {
        const int pos = atomicAdd(&cur[mem[a]], 1);
        sorted[pos] = a;
    }
}

// ---------------------------------------------------------------------------
// Per-segment: dense 64->128 + ReLU + BN2, register reduce (sum,max), tanh.
// One 128-thread block per segment; thread c owns channel c, W column in VGPRs.
// ---------------------------------------------------------------------------
__global__ __launch_bounds__(128) void seg_reduce_kernel(
    const float* __restrict__ p,
    const int* __restrict__ sorted, const int* __restrict__ off,
    const int* __restrict__ cnt,
    const float* __restrict__ Wd, const float* __restrict__ bd,
    const float* __restrict__ bng, const float* __restrict__ bnb,
    const float* __restrict__ bnm, const float* __restrict__ bnv,
    float* __restrict__ nf)
{
    __shared__ __align__(16) float rows[8][64];
    const int m = blockIdx.x;
    const int c = threadIdx.x;

    float wcol[64];
    #pragma unroll
    for (int k = 0; k < 64; ++k) wcol[k] = Wd[k * 128 + c];

    const float bias = bd[c];
    const float gmv = bng[c], btv = bnb[c], mnv = bnm[c];
    const float rsv = rsqrtf(bnv[c] + 1e-3f);

    const int n = cnt[m];
    const int start = off[m];

    float s = 0.f, mx = -INFINITY;
    for (int base = 0; base < n; base += 8) {
        const int take = min(8, n - base);
        __syncthreads();
        for (int e = c; e < take * 16; e += 128) {
            const int r = e >> 4, k4 = e & 15;
            reinterpret_cast<float4*>(rows[r])[k4] =
                reinterpret_cast<const float4*>(p + (size_t)sorted[start + base + r] * 64)[k4];
        }
        __syncthreads();
        for (int r = 0; r < take; ++r) {
            float acc = bias;
            #pragma unroll
            for (int k = 0; k < 64; ++k) acc = fmaf(rows[r][k], wcol[k], acc);
            float v = fmaxf(acc, 0.f);
            v = (v - mnv) * rsv * gmv + btv;
            s += v;
            mx = fmaxf(mx, v);
        }
    }
    nf[(size_t)m * 256 + c]       = tanhf(s);
    nf[(size_t)m * 256 + 128 + c] = tanhf(mx);
}

// fd0: h = relu(nf @ W + b), 32768x256 @ 256x256. 64x64 tile per block.
__global__ __launch_bounds__(256) void fd0_kernel(
    const float* __restrict__ nf, const float* __restrict__ W, const float* __restrict__ b,
    float* __restrict__ h)
{
    __shared__ __align__(16) float sx[256][64];
    const int t = threadIdx.x;
    const int r0 = (blockIdx.x >> 2) * 64;
    const int c0 = (blockIdx.x & 3) * 64;
    for (int e = t; e < 64 * 256; e += 256) {
        const int ri = e >> 8, k = e & 255;
        sx[k][ri] = nf[(size_t)(r0 + ri) * 256 + k];
    }
    __syncthreads();
    const int c = t & 63, g = t >> 6;
    float acc[16];
    #pragma unroll
    for (int i = 0; i < 16; ++i) acc[i] = 0.f;
    for (int k = 0; k < 256; ++k) {
        const float w = W[(size_t)k * 256 + c0 + c];
        #pragma unroll
        for (int ii = 0; ii < 4; ++ii) {
            const float4 v = *reinterpret_cast<const float4*>(&sx[k][g * 16 + ii * 4]);
            acc[ii*4+0] = fmaf(v.x, w, acc[ii*4+0]);
            acc[ii*4+1] = fmaf(v.y, w, acc[ii*4+1]);
            acc[ii*4+2] = fmaf(v.z, w, acc[ii*4+2]);
            acc[ii*4+3] = fmaf(v.w, w, acc[ii*4+3]);
        }
    }
    const float bb = b[c0 + c];
    #pragma unroll
    for (int i = 0; i < 16; ++i)
        h[(size_t)(r0 + g * 16 + i) * 256 + c0 + c] = fmaxf(acc[i] + bb, 0.f);
}

// rd: logits = h @ W + b (256->24), then pairwise softmax. 32 rows x 12 pairs.
__global__ __launch_bounds__(384) void rd_kernel(
    const float* __restrict__ h, const float* __restrict__ W, const float* __restrict__ b,
    float* __restrict__ outP, float* __restrict__ outL)
{
    __shared__ float sh[32][257];
    const int t = threadIdx.x;
    const int r0 = blockIdx.x * 32;
    for (int e = t; e < 32 * 256; e += 384) {
        const int ri = e >> 8, k = e & 255;
        sh[ri][k] = h[(size_t)(r0 + ri) * 256 + k];
    }
    __syncthreads();
    const int r = t / 12, pj = t % 12;
    float a0 = b[2 * pj], a1 = b[2 * pj + 1];
    for (int k = 0; k < 256; ++k) {
        const float hv = sh[r][k];
        a0 = fmaf(hv, W[k * 24 + 2 * pj],     a0);
        a1 = fmaf(hv, W[k * 24 + 2 * pj + 1], a1);
    }
    const size_t m = (size_t)(r0 + r);
    outL[m * 24 + 2 * pj]     = a0;
    outL[m * 24 + 2 * pj + 1] = a1;
    const float mx = fmaxf(a0, a1);
    const float e0 = expf(a0 - mx), e1 = expf(a1 - mx);
    const float inv = 1.f / (e0 + e1);
    outP[m * 24 + 2 * pj]     = e0 * inv;
    outP[m * 24 + 2 * pj + 1] = e1 * inv;
}

// ---------------------------------------------------------------------------
// per-layer launcher helpers
// ---------------------------------------------------------------------------
template<int CI>
void launch_conv_layer(const float* x, const int* const* adj,
                       const float* W, const float* B,
                       const float* g, const float* b, const float* m, const float* v,
                       float* out, hipStream_t stream)
{
    #define CONV_D(D) conv_kernel<CI, D><<<(kCounts[D] + 63) / 64, 256, 0, stream>>>( \
        x, adj[D - 1], kCounts[D], kStarts[D], W, B, g, b, m, v, out)
    conv0_kernel<CI><<<(kCounts[0] + 63) / 64, 256, 0, stream>>>(
        x, kCounts[0], kStarts[0], W, B, g, b, m, v, out);
    CONV_D(1); CONV_D(2); CONV_D(3); CONV_D(4); CONV_D(5);
    CONV_D(6); CONV_D(7); CONV_D(8); CONV_D(9); CONV_D(10);
    #undef CONV_D
}

void launch_pool_layer(const float* z, const int* const* adj, float* p, hipStream_t stream)
{
    #define POOL_D(D) pool_kernel<D><<<(kCounts[D] + 3) / 4, 256, 0, stream>>>( \
        z, adj[D - 1], kCounts[D], kStarts[D], p)
    copy0_kernel<<<625, 256, 0, stream>>>(z, p);
    POOL_D(1); POOL_D(2); POOL_D(3); POOL_D(4); POOL_D(5);
    POOL_D(6); POOL_D(7); POOL_D(8); POOL_D(9); POOL_D(10);
    #undef POOL_D
}

} // namespace

extern "C" void kernel_launch(void* const* d_in, const int* in_sizes, int n_in,
                              void* d_out, int out_size, void* d_ws, size_t ws_size,
                              hipStream_t stream)
{
    const float* x       = (const float*)d_in[0];
    const int*   mem     = (const int*)d_in[2];
    const int* adj[10];
    for (int d = 0; d < 10; ++d) adj[d] = (const int*)d_in[4 + d];
    const float* gc0_W = (const float*)d_in[14];
    const float* gc0_b = (const float*)d_in[15];
    const float* gc1_W = (const float*)d_in[16];
    const float* gc1_b = (const float*)d_in[17];
    const float* bn0g = (const float*)d_in[18], *bn0b = (const float*)d_in[19];
    const float* bn0m = (const float*)d_in[20], *bn0v = (const float*)d_in[21];
    const float* bn1g = (const float*)d_in[22], *bn1b = (const float*)d_in[23];
    const float* bn1m = (const float*)d_in[24], *bn1v = (const float*)d_in[25];
    const float* bn2g = (const float*)d_in[26], *bn2b = (const float*)d_in[27];
    const float* bn2m = (const float*)d_in[28], *bn2v = (const float*)d_in[29];
    const float* dW   = (const float*)d_in[30], *db   = (const float*)d_in[31];
    const float* fW   = (const float*)d_in[32], *fb   = (const float*)d_in[33];
    const float* rW   = (const float*)d_in[34], *rb   = (const float*)d_in[35];

    float* zbuf = (float*)d_ws;
    float* pbuf = zbuf + (size_t)NATOMS * 64;
    float* hbuf = pbuf + (size_t)NATOMS * 64;
    int*   cnt    = (int*)(hbuf + (size_t)NBATCH * 256);
    int*   offp   = cnt + NBATCH;
    int*   cur    = offp + NBATCH;
    int*   sorted = cur + NBATCH;

    float* outP = (float*)d_out;
    float* outL = outP + (size_t)NBATCH * 24;
    float* nfb  = outL + (size_t)NBATCH * 24;

    // counting sort by membership (independent of conv path)
    hipMemsetAsync(cnt, 0, NBATCH * sizeof(int), stream);
    hist_kernel<<<(NATOMS + 255) / 256, 256, 0, stream>>>(mem, cnt);
    scan_kernel<<<1, 512, 0, stream>>>(cnt, offp, cur);
    scatter_kernel<<<(NATOMS + 255) / 256, 256, 0, stream>>>(mem, cur, sorted);

    // layer 1: conv(75->64)+relu+bn0 -> pool
    launch_conv_layer<75>(x, adj, gc0_W, gc0_b, bn0g, bn0b, bn0m, bn0v, zbuf, stream);
    launch_pool_layer(zbuf, adj, pbuf, stream);

    // layer 2: conv(64->64)+relu+bn1 -> pool
    launch_conv_layer<64>(pbuf, adj, gc1_W, gc1_b, bn1g, bn1b, bn1m, bn1v, zbuf, stream);
    launch_pool_layer(zbuf, adj, pbuf, stream);

    // per-segment dense+relu+bn2 + sum/max reduce + tanh -> nf
    seg_reduce_kernel<<<NBATCH, 128, 0, stream>>>(pbuf, sorted, offp, cnt,
                                                  dW, db, bn2g, bn2b, bn2m, bn2v, nfb);
    // h = relu(nf @ fd0_W + fd0_b)
    fd0_kernel<<<(NBATCH / 64) * 4, 256, 0, stream>>>(nfb, fW, fb, hbuf);
    // logits + softmax
    rd_kernel<<<NBATCH / 32, 384, 0, stream>>>(hbuf, rW, rb, outP, outL);
}